// Round 4
// baseline (275.684 us; speedup 1.0000x reference)
//
#include <hip/hip_runtime.h>
#include <hip/hip_bf16.h>

// SemanticDecoder: mean = b@Wmu+bmu; s = b@Wsig+bsig; var = s*s;
// sample = mean + |s|*eps.  B=65536, K=64, D=300. f32 in/out.
// Outputs concatenated: [sample, mean, var], each B*D.
//
// R4: MFMA restructure. Kernel 1 packs W (f32) into f16 MFMA-B fragments in
// d_ws. Main kernel: 8 waves/block, wave = 16-row tile; A-frags direct from
// global (K-permutation identical for A and B => any consistent k-map is
// correct); B-frags from LDS (linear, conflict-free); bias folded into the
// MFMA accumulator init; epilogue = var/sample + nontemporal stores.

#define B_ROWS 65536
#define K_DIM 64
#define D_DIM 300
#define NFRAG 19          // ceil(300/16); frag 18 has cols 288..303 (mask >=300)
#define HALF0_NF 10
#define LDS_FRAGS 10
#define MAIN_THREADS 512
#define ROWS_PER_BLOCK 128

typedef __fp16 half2v __attribute__((ext_vector_type(2)));
typedef __fp16 half8v __attribute__((ext_vector_type(8)));
typedef float  f32x4  __attribute__((ext_vector_type(4)));

__device__ __forceinline__ half8v pack8(float4 x, float4 y) {
    half2v p0 = __builtin_amdgcn_cvt_pkrtz(x.x, x.y);
    half2v p1 = __builtin_amdgcn_cvt_pkrtz(x.z, x.w);
    half2v p2 = __builtin_amdgcn_cvt_pkrtz(y.x, y.y);
    half2v p3 = __builtin_amdgcn_cvt_pkrtz(y.z, y.w);
    half8v r;
    r[0] = p0[0]; r[1] = p0[1]; r[2] = p1[0]; r[3] = p1[1];
    r[4] = p2[0]; r[5] = p2[1]; r[6] = p3[0]; r[7] = p3[1];
    return r;
}

// ---- kernel 1: pack W[64][300] f32 -> f16 B-fragments --------------------
// unit t = ((m*NFRAG + f)*2 + s)*64 + lane ; holds 8 f16:
//   W_m[k = s*32 + (lane>>4)*8 + e][col = f*16 + (lane&15)], e = 0..7
__global__ void pack_w_kernel(const float* __restrict__ Wmu,
                              const float* __restrict__ Wsig,
                              half8v* __restrict__ wpack)
{
    const int t = blockIdx.x * blockDim.x + threadIdx.x;
    const int total = 2 * NFRAG * 2 * 64;  // 4864
    if (t >= total) return;
    const int lane = t & 63;
    const int fs   = t >> 6;
    const int s    = fs & 1;
    const int mf   = fs >> 1;
    const int m    = mf / NFRAG;
    const int f    = mf - m * NFRAG;
    const int col  = f * 16 + (lane & 15);
    const int k0   = s * 32 + (lane >> 4) * 8;
    const float* W = m ? Wsig : Wmu;
    half8v o;
    #pragma unroll
    for (int e = 0; e < 8; ++e) {
        float v = (col < D_DIM) ? W[(size_t)(k0 + e) * D_DIM + col] : 0.f;
        o[e] = (__fp16)v;
    }
    wpack[t] = o;
}

// ---- main kernel ---------------------------------------------------------
__global__ __launch_bounds__(MAIN_THREADS, 4) void sem_dec_main(
    const float* __restrict__ b,
    const float* __restrict__ bmu,
    const float* __restrict__ bsig,
    const float* __restrict__ eps,
    const half8v* __restrict__ wpack,
    float* __restrict__ out)
{
    __shared__ half8v wlds[2 * LDS_FRAGS * 2 * 64];  // 40960 B

    const int tid     = threadIdx.x;
    const int lane    = tid & 63;
    const int wid     = tid >> 6;             // 0..7, one 16-row tile per wave
    const int half_id = blockIdx.y;           // 0: frags 0-9, 1: frags 10-18
    const int f0      = half_id * HALF0_NF;
    const int nf      = half_id ? (NFRAG - HALF0_NF) : HALF0_NF;
    const int rowbase = blockIdx.x * ROWS_PER_BLOCK + wid * 16;

    // A fragments: row = lane&15, k = (lane>>4)*8 + e (+32 for slice 1)
    const int arow = lane & 15;
    const int kg   = lane >> 4;
    const float* bp = b + (size_t)(rowbase + arow) * K_DIM + kg * 8;
    float4 v0 = *reinterpret_cast<const float4*>(bp);
    float4 v1 = *reinterpret_cast<const float4*>(bp + 4);
    float4 v2 = *reinterpret_cast<const float4*>(bp + 32);
    float4 v3 = *reinterpret_cast<const float4*>(bp + 36);
    half8v a0 = pack8(v0, v1);
    half8v a1 = pack8(v2, v3);

    // stage this half's packed weights -> LDS (contiguous per matrix)
    {
        const int n = nf * 2 * 64;            // 1280 or 1152 units of 16 B
        #pragma unroll
        for (int m = 0; m < 2; ++m) {
            const half8v* src = wpack + (m * NFRAG + f0) * 2 * 64;
            half8v* dst = wlds + m * (LDS_FRAGS * 2 * 64);
            for (int i = tid; i < n; i += MAIN_THREADS)
                dst[i] = src[i];
        }
    }
    __syncthreads();

    const size_t BD = (size_t)B_ROWS * D_DIM;
    const int ccol = lane & 15;
    const int crow = (lane >> 4) * 4;         // + reg 0..3 (m89-verified C map)

    #pragma unroll
    for (int fi = 0; fi < LDS_FRAGS; ++fi) {
        const int c = (f0 + fi) * 16 + ccol;
        const bool cval = (c < D_DIM);        // frag 18 tail + half1 fi=9 pad
        half8v wm0 = wlds[((0 * LDS_FRAGS + fi) * 2 + 0) * 64 + lane];
        half8v wm1 = wlds[((0 * LDS_FRAGS + fi) * 2 + 1) * 64 + lane];
        half8v ws0 = wlds[((1 * LDS_FRAGS + fi) * 2 + 0) * 64 + lane];
        half8v ws1 = wlds[((1 * LDS_FRAGS + fi) * 2 + 1) * 64 + lane];
        const float biasm = cval ? bmu[c] : 0.f;
        const float biass = cval ? bsig[c] : 0.f;
        float ev[4];
        #pragma unroll
        for (int r = 0; r < 4; ++r)
            ev[r] = cval ? __builtin_nontemporal_load(
                        &eps[(size_t)(rowbase + crow + r) * D_DIM + c]) : 0.f;
        f32x4 accm = {biasm, biasm, biasm, biasm};
        f32x4 accs = {biass, biass, biass, biass};
        accm = __builtin_amdgcn_mfma_f32_16x16x32_f16(a0, wm0, accm, 0, 0, 0);
        accm = __builtin_amdgcn_mfma_f32_16x16x32_f16(a1, wm1, accm, 0, 0, 0);
        accs = __builtin_amdgcn_mfma_f32_16x16x32_f16(a0, ws0, accs, 0, 0, 0);
        accs = __builtin_amdgcn_mfma_f32_16x16x32_f16(a1, ws1, accs, 0, 0, 0);
        if (cval) {
            #pragma unroll
            for (int r = 0; r < 4; ++r) {
                const float mean = accm[r];
                const float sv   = accs[r];
                const float var  = sv * sv;
                const float sample = fmaf(fabsf(sv), ev[r], mean);
                const size_t o = (size_t)(rowbase + crow + r) * D_DIM + c;
                __builtin_nontemporal_store(sample, &out[o]);
                __builtin_nontemporal_store(mean,   &out[o + BD]);
                __builtin_nontemporal_store(var,    &out[o + 2 * BD]);
            }
        }
    }
}

extern "C" void kernel_launch(void* const* d_in, const int* in_sizes, int n_in,
                              void* d_out, int out_size, void* d_ws, size_t ws_size,
                              hipStream_t stream) {
    const float* b    = (const float*)d_in[0];
    // d_in[1] = labels (unused by the reference outputs)
    const float* Wmu  = (const float*)d_in[2];
    const float* bmu  = (const float*)d_in[3];
    const float* Wsig = (const float*)d_in[4];
    const float* bsig = (const float*)d_in[5];
    const float* eps  = (const float*)d_in[6];
    float* out = (float*)d_out;
    half8v* wpack = (half8v*)d_ws;            // 4864 * 16 B = 77824 B

    hipLaunchKernelGGL(pack_w_kernel, dim3(19), dim3(256), 0, stream,
                       Wmu, Wsig, wpack);
    hipLaunchKernelGGL(sem_dec_main, dim3(B_ROWS / ROWS_PER_BLOCK, 2),
                       dim3(MAIN_THREADS), 0, stream,
                       b, bmu, bsig, eps, wpack, out);
}

// Round 5
// 130.345 us; speedup vs baseline: 2.1150x; 2.1150x over previous
//
#include <hip/hip_runtime.h>
#include <hip/hip_bf16.h>

// SemanticDecoder: mean = b@Wmu+bmu; s = b@Wsig+bsig; var = s*s;
// sample = mean + |s|*eps.  B=65536, K=64, D=300. f32 in/out.
// Outputs concatenated: [sample, mean, var], each B*D.
//
// R5: back to R3's thread-per-column structure (clean contiguous row writes,
// WRITE_SIZE was exactly ideal 237 MB). Fix R3's weight eviction (VGPR=52
// proved weights were rematerialized per row): pre-transpose W to [m][d][k]
// f16 in d_ws so each thread loads its column as 8x dwordx4 -> register
// resident; relax launch_bounds to (320,2) so the allocator has 256 VGPRs.

#define B_ROWS 65536
#define K_DIM 64
#define D_DIM 300
#define ROWS_PER_BLOCK 64
#define THREADS 320   // 5 waves; threads 0..299 own one output column each

typedef __fp16 half2v __attribute__((ext_vector_type(2)));
typedef __fp16 half4v __attribute__((ext_vector_type(4)));
typedef __fp16 half8v __attribute__((ext_vector_type(8)));

__device__ __forceinline__ float dot2h(half2v a, half2v b, float c) {
#if __has_builtin(__builtin_amdgcn_fdot2)
    return __builtin_amdgcn_fdot2(a, b, c, false);
#else
    return fmaf((float)a[0], (float)b[0], fmaf((float)a[1], (float)b[1], c));
#endif
}

// ---- kernel 1: W[64][300] f32 -> wp[m][d][k] f16 (transposed, packed) ----
__global__ void pack_wT_kernel(const float* __restrict__ Wmu,
                               const float* __restrict__ Wsig,
                               __fp16* __restrict__ wp)
{
    const int t = blockIdx.x * blockDim.x + threadIdx.x;
    if (t >= 2 * D_DIM * (K_DIM / 8)) return;   // 4800 units of 8 k-values
    const int g = t & 7;
    const int d = (t >> 3) % D_DIM;
    const int m = t / (D_DIM * 8);
    const float* W = m ? Wsig : Wmu;
    half8v o;
    #pragma unroll
    for (int e = 0; e < 8; ++e)
        o[e] = (__fp16)W[(size_t)(g * 8 + e) * D_DIM + d];
    *reinterpret_cast<half8v*>(&wp[((size_t)m * D_DIM + d) * K_DIM + g * 8]) = o;
}

// ---- main kernel ---------------------------------------------------------
__global__ __launch_bounds__(THREADS, 2) void sem_dec_kernel(
    const float* __restrict__ b,
    const float* __restrict__ bmu,
    const float* __restrict__ bsig,
    const float* __restrict__ eps,
    const __fp16* __restrict__ wp,
    float* __restrict__ out)
{
    __shared__ __fp16 lds_bh[ROWS_PER_BLOCK * K_DIM]; // 8 KB packed f16

    const int tid  = threadIdx.x;
    const int row0 = blockIdx.x * ROWS_PER_BLOCK;

    // ---- stage b[row0:row0+64, 0:64] -> LDS as f16, coalesced float4 in ----
    {
        const float4* gb = reinterpret_cast<const float4*>(b + (size_t)row0 * K_DIM);
        const int n4 = ROWS_PER_BLOCK * K_DIM / 4; // 1024
        for (int i = tid; i < n4; i += THREADS) {
            float4 v = gb[i];
            half2v p0 = __builtin_amdgcn_cvt_pkrtz(v.x, v.y);
            half2v p1 = __builtin_amdgcn_cvt_pkrtz(v.z, v.w);
            half4v p = __builtin_shufflevector(p0, p1, 0, 1, 2, 3);
            *reinterpret_cast<half4v*>(&lds_bh[4 * i]) = p; // ds_write_b64
        }
    }
    __syncthreads();

    if (tid >= D_DIM) return;
    const int d = tid;

    // ---- weight column -> 16 x half8v VGPRs via dwordx4 vector loads ----
    half8v wmu_r[K_DIM / 8], wsig_r[K_DIM / 8];
    {
        const half8v* wm = reinterpret_cast<const half8v*>(wp + (size_t)d * K_DIM);
        const half8v* ws = reinterpret_cast<const half8v*>(
            wp + ((size_t)D_DIM + d) * K_DIM);
        #pragma unroll
        for (int j = 0; j < K_DIM / 8; ++j) { wmu_r[j] = wm[j]; wsig_r[j] = ws[j]; }
    }
    const float bm = bmu[d];
    const float bs = bsig[d];

    const size_t BD = (size_t)B_ROWS * D_DIM;
    float* __restrict__ out_sample = out;
    float* __restrict__ out_mean   = out + BD;
    float* __restrict__ out_var    = out + 2 * BD;

    size_t ed = (size_t)row0 * D_DIM + d;

    // eps software pipeline: one 4-row group of lead
    float e0 = eps[ed];
    float e1 = eps[ed +     D_DIM];
    float e2 = eps[ed + 2 * D_DIM];
    float e3 = eps[ed + 3 * D_DIM];

    for (int rg = 0; rg < ROWS_PER_BLOCK; rg += 4) {
        const float f0 = e0, f1 = e1, f2 = e2, f3 = e3;
        if (rg + 4 < ROWS_PER_BLOCK) {
            const size_t p = ed + 4 * (size_t)D_DIM;
            e0 = eps[p];
            e1 = eps[p +     D_DIM];
            e2 = eps[p + 2 * D_DIM];
            e3 = eps[p + 3 * D_DIM];
        }
        #pragma unroll
        for (int j = 0; j < 4; ++j) {
            const float e = (j == 0) ? f0 : (j == 1) ? f1 : (j == 2) ? f2 : f3;
            const half8v* bp =
                reinterpret_cast<const half8v*>(&lds_bh[(rg + j) * K_DIM]);
            // 4 independent dot chains (2 mu, 2 sig)
            float am0 = bm, am1 = 0.f, as0 = bs, as1 = 0.f;
            #pragma unroll
            for (int kk = 0; kk < K_DIM / 8; ++kk) {   // 8 broadcast b128 reads
                half8v r = bp[kk];
                half2v q0 = __builtin_shufflevector(r, r, 0, 1);
                half2v q1 = __builtin_shufflevector(r, r, 2, 3);
                half2v q2 = __builtin_shufflevector(r, r, 4, 5);
                half2v q3 = __builtin_shufflevector(r, r, 6, 7);
                half8v wm = wmu_r[kk];
                half8v ws = wsig_r[kk];
                am0 = dot2h(q0, __builtin_shufflevector(wm, wm, 0, 1), am0);
                am1 = dot2h(q1, __builtin_shufflevector(wm, wm, 2, 3), am1);
                as0 = dot2h(q0, __builtin_shufflevector(ws, ws, 0, 1), as0);
                as1 = dot2h(q1, __builtin_shufflevector(ws, ws, 2, 3), as1);
                am0 = dot2h(q2, __builtin_shufflevector(wm, wm, 4, 5), am0);
                am1 = dot2h(q3, __builtin_shufflevector(wm, wm, 6, 7), am1);
                as0 = dot2h(q2, __builtin_shufflevector(ws, ws, 4, 5), as0);
                as1 = dot2h(q3, __builtin_shufflevector(ws, ws, 6, 7), as1);
            }
            const float mean   = am0 + am1;
            const float s      = as0 + as1;
            const float var    = s * s;
            const float sample = fmaf(fabsf(s), e, mean);
            const size_t o = ed + (size_t)j * D_DIM;
            out_sample[o] = sample;
            out_mean[o]   = mean;
            out_var[o]    = var;
        }
        ed += 4 * (size_t)D_DIM;
    }
}

extern "C" void kernel_launch(void* const* d_in, const int* in_sizes, int n_in,
                              void* d_out, int out_size, void* d_ws, size_t ws_size,
                              hipStream_t stream) {
    const float* b    = (const float*)d_in[0];
    // d_in[1] = labels (unused by the reference outputs)
    const float* Wmu  = (const float*)d_in[2];
    const float* bmu  = (const float*)d_in[3];
    const float* Wsig = (const float*)d_in[4];
    const float* bsig = (const float*)d_in[5];
    const float* eps  = (const float*)d_in[6];
    float* out = (float*)d_out;
    __fp16* wp = (__fp16*)d_ws;               // 2*300*64*2 B = 76800 B

    hipLaunchKernelGGL(pack_wT_kernel, dim3(19), dim3(256), 0, stream,
                       Wmu, Wsig, wp);
    hipLaunchKernelGGL(sem_dec_kernel, dim3(B_ROWS / ROWS_PER_BLOCK),
                       dim3(THREADS), 0, stream,
                       b, bmu, bsig, eps, wp, out);
}